// Round 1
// baseline (4245.195 us; speedup 1.0000x reference)
//
#include <hip/hip_runtime.h>
#include <cfloat>
#include <cmath>

#define NROWS 65536
#define DDIM 256
#define KDIM 4096

constexpr float EPSV = 1e-5f;
constexpr float DECAYV = 0.99f;
constexpr float MOMV = 0.1f;

// ---------------- workspace layout (float offsets) ----------------
constexpr size_t WS_PARTSUM = 0;                              // [256][256]
constexpr size_t WS_PARTSQ  = WS_PARTSUM + 256 * DDIM;        // [256][256]
constexpr size_t WS_MEAN    = WS_PARTSQ + 256 * DDIM;         // [256]
constexpr size_t WS_RSTD    = WS_MEAN + DDIM;                 // [256]
constexpr size_t WS_NRMEAN  = WS_RSTD + DDIM;                 // [256]
constexpr size_t WS_NRVAR   = WS_NRMEAN + DDIM;               // [256]
constexpr size_t WS_BVEC    = WS_NRVAR + DDIM;                // [4096]
constexpr size_t WS_NCSRAW  = WS_BVEC + KDIM;                 // [4096]
constexpr size_t WS_NTOT    = WS_NCSRAW + KDIM;               // [1] (+pad)
constexpr size_t WS_IDX     = WS_NTOT + 64;                   // int[65536]
constexpr size_t WS_COUNTS  = WS_IDX + NROWS;                 // [4096]   (zeroed)
constexpr size_t WS_DWRAW   = WS_COUNTS + KDIM;               // [4096*256] (zeroed, contiguous w/ counts)
constexpr size_t WS_EPT     = WS_DWRAW + (size_t)KDIM * DDIM; // e' transposed [256][4096]
constexpr size_t WS_TOTALF  = WS_EPT + (size_t)DDIM * KDIM;   // ~9.2 MB

// ---------------- output layout (float offsets) ----------------
constexpr size_t O_IDX   = 0;                                 // [65536]
constexpr size_t O_EMB   = NROWS;                             // [4096*256]
constexpr size_t O_EOUT  = O_EMB + (size_t)KDIM * DDIM;       // [4096*256]
constexpr size_t O_CS    = O_EOUT + (size_t)KDIM * DDIM;      // [4096]
constexpr size_t O_EMAW  = O_CS + KDIM;                       // [4096*256]
constexpr size_t O_RMEAN = O_EMAW + (size_t)KDIM * DDIM;      // [256]
constexpr size_t O_RVAR  = O_RMEAN + DDIM;                    // [256]

// ================= K1: per-block column sums =================
__global__ __launch_bounds__(256) void k_bn_partial(const float* __restrict__ x,
                                                    float* __restrict__ ws) {
    const int d = threadIdx.x;
    const int b = blockIdx.x;  // 256 blocks
    float s = 0.f, sq = 0.f;
    for (int r = b; r < NROWS; r += 256) {
        const float v = x[(size_t)r * DDIM + d];
        s += v;
        sq += v * v;
    }
    ws[WS_PARTSUM + (size_t)b * DDIM + d] = s;
    ws[WS_PARTSQ  + (size_t)b * DDIM + d] = sq;
}

// ================= K2: finalize BN stats =================
__global__ __launch_bounds__(256) void k_bn_final(const float* __restrict__ rmean_in,
                                                  const float* __restrict__ rvar_in,
                                                  float* __restrict__ ws,
                                                  float* __restrict__ out) {
    const int d = threadIdx.x;
    float s = 0.f, sq = 0.f;
    for (int b = 0; b < 256; ++b) {
        s  += ws[WS_PARTSUM + (size_t)b * DDIM + d];
        sq += ws[WS_PARTSQ  + (size_t)b * DDIM + d];
    }
    const float mean = s / (float)NROWS;
    float var = sq / (float)NROWS - mean * mean;
    var = fmaxf(var, 0.f);
    const float rstd = 1.0f / sqrtf(var + EPSV);
    const float nrm  = (1.0f - MOMV) * rmean_in[d] + MOMV * mean;
    const float varu = var * ((float)NROWS / (float)(NROWS - 1));
    const float nrv  = (1.0f - MOMV) * rvar_in[d] + MOMV * varu;
    ws[WS_MEAN + d] = mean;
    ws[WS_RSTD + d] = rstd;
    ws[WS_NRMEAN + d] = nrm;
    ws[WS_NRVAR + d] = nrv;
    out[O_RMEAN + d] = nrm;
    out[O_RVAR + d] = nrv;
}

// ================= K3: e' = rstd*e (transposed [D][K]) and b_k =================
__global__ __launch_bounds__(256) void k_eprime(const float* __restrict__ emb,
                                                float* __restrict__ ws) {
    __shared__ float red[256];
    const int k = blockIdx.x;   // 4096 blocks
    const int d = threadIdx.x;
    const float e  = emb[(size_t)k * DDIM + d];
    const float rs = ws[WS_RSTD + d];
    const float mn = ws[WS_MEAN + d];
    ws[WS_EPT + (size_t)d * KDIM + k] = e * rs;
    red[d] = e * e + 2.0f * mn * rs * e;   // ||e||^2 + 2*c_k terms
    __syncthreads();
    for (int s = 128; s > 0; s >>= 1) {
        if (d < s) red[d] += red[d + s];
        __syncthreads();
    }
    if (d == 0) ws[WS_BVEC + k] = red[0];
}

// ================= K4: fused distance-GEMM + argmin =================
// 64 rows x 64 cols per tile, full-D LDS staging (transposed, stride 68 for
// b128-aligned conflict-free reads). 4x4 register micro-tile per thread.
__global__ __launch_bounds__(256) void k_argmin(const float* __restrict__ x,
                                                const float* __restrict__ ws,
                                                float* __restrict__ out,
                                                int* __restrict__ idx_int) {
    extern __shared__ float lds[];
    float* xT   = lds;                    // [256][68]
    float* eT   = lds + 256 * 68;         // [256][68]
    float* rval = lds + 2 * 256 * 68;     // [64*16]
    int*   ridx = (int*)(rval + 64 * 16); // [64*16]

    const int t  = threadIdx.x;
    const int r0 = blockIdx.x * 64;
    const float* __restrict__ ept  = ws + WS_EPT;
    const float* __restrict__ bvec = ws + WS_BVEC;

    // stage x transposed: xT[d][r], d = t (coalesced global reads)
    for (int rr = 0; rr < 64; ++rr)
        xT[t * 68 + rr] = x[(size_t)(r0 + rr) * DDIM + t];

    float best[4];
    int   bidx[4];
#pragma unroll
    for (int i = 0; i < 4; ++i) { best[i] = FLT_MAX; bidx[i] = 0; }

    const int rq = 4 * (t & 15);   // row quad within tile
    const int cq = 4 * (t >> 4);   // col quad within tile
    const int kk = t & 63;
    const int wv = t >> 6;

    for (int k0 = 0; k0 < KDIM; k0 += 64) {
        __syncthreads();
        // stage e' tile: eT[d][kk] from transposed global layout (coalesced)
#pragma unroll 4
        for (int i = 0; i < 64; ++i) {
            const int d = i * 4 + wv;
            eT[d * 68 + kk] = ept[(size_t)d * KDIM + k0 + kk];
        }
        __syncthreads();

        float acc[4][4];
#pragma unroll
        for (int i = 0; i < 4; ++i)
#pragma unroll
            for (int j = 0; j < 4; ++j) acc[i][j] = 0.f;

#pragma unroll 4
        for (int d = 0; d < DDIM; ++d) {
            const float4 xv = *reinterpret_cast<const float4*>(&xT[d * 68 + rq]);
            const float4 ev = *reinterpret_cast<const float4*>(&eT[d * 68 + cq]);
            acc[0][0] = fmaf(xv.x, ev.x, acc[0][0]);
            acc[0][1] = fmaf(xv.x, ev.y, acc[0][1]);
            acc[0][2] = fmaf(xv.x, ev.z, acc[0][2]);
            acc[0][3] = fmaf(xv.x, ev.w, acc[0][3]);
            acc[1][0] = fmaf(xv.y, ev.x, acc[1][0]);
            acc[1][1] = fmaf(xv.y, ev.y, acc[1][1]);
            acc[1][2] = fmaf(xv.y, ev.z, acc[1][2]);
            acc[1][3] = fmaf(xv.y, ev.w, acc[1][3]);
            acc[2][0] = fmaf(xv.z, ev.x, acc[2][0]);
            acc[2][1] = fmaf(xv.z, ev.y, acc[2][1]);
            acc[2][2] = fmaf(xv.z, ev.z, acc[2][2]);
            acc[2][3] = fmaf(xv.z, ev.w, acc[2][3]);
            acc[3][0] = fmaf(xv.w, ev.x, acc[3][0]);
            acc[3][1] = fmaf(xv.w, ev.y, acc[3][1]);
            acc[3][2] = fmaf(xv.w, ev.z, acc[3][2]);
            acc[3][3] = fmaf(xv.w, ev.w, acc[3][3]);
        }

        float bl[4];
#pragma unroll
        for (int j = 0; j < 4; ++j) bl[j] = bvec[k0 + cq + j];
#pragma unroll
        for (int i = 0; i < 4; ++i) {
#pragma unroll
            for (int j = 0; j < 4; ++j) {
                const float s = bl[j] - 2.0f * acc[i][j];
                const int ki = k0 + cq + j;
                if (s < best[i]) { best[i] = s; bidx[i] = ki; }  // strict < keeps first min
            }
        }
    }

    __syncthreads();
    const int g = t >> 4;
#pragma unroll
    for (int i = 0; i < 4; ++i) {
        rval[(rq + i) * 16 + g] = best[i];
        ridx[(rq + i) * 16 + g] = bidx[i];
    }
    __syncthreads();
    if (t < 64) {
        float bv = rval[t * 16];
        int   bi = ridx[t * 16];
        for (int gg = 1; gg < 16; ++gg) {
            const float v = rval[t * 16 + gg];
            const int  ii = ridx[t * 16 + gg];
            if (v < bv || (v == bv && ii < bi)) { bv = v; bi = ii; }
        }
        out[O_IDX + r0 + t] = (float)bi;
        idx_int[r0 + t] = bi;
    }
}

// ================= K5: scatter raw-x sums + counts =================
__global__ __launch_bounds__(256) void k_scatter(const float* __restrict__ x,
                                                 const int* __restrict__ idx_int,
                                                 float* __restrict__ ws) {
    float* counts = ws + WS_COUNTS;
    float* dwraw  = ws + WS_DWRAW;
    const int t = threadIdx.x;
    for (int r = blockIdx.x; r < NROWS; r += gridDim.x) {
        const int k = idx_int[r];
        atomicAdd(&dwraw[(size_t)k * DDIM + t], x[(size_t)r * DDIM + t]);
        if (t == 0) atomicAdd(&counts[k], 1.0f);
    }
}

// ================= K6a: EMA cluster size raw + n_total (single block, deterministic) =================
__global__ __launch_bounds__(256) void k_ema_cs(const float* __restrict__ cs_in,
                                                float* __restrict__ ws) {
    __shared__ float red[256];
    const int t = threadIdx.x;
    float part = 0.f;
    for (int k = t; k < KDIM; k += 256) {
        const float ncs = cs_in[k] * DECAYV + (1.0f - DECAYV) * ws[WS_COUNTS + k];
        ws[WS_NCSRAW + k] = ncs;
        part += ncs;
    }
    red[t] = part;
    __syncthreads();
    for (int s = 128; s > 0; s >>= 1) {
        if (t < s) red[t] += red[t + s];
        __syncthreads();
    }
    if (t == 0) ws[WS_NTOT] = red[0];
}

// ================= K6b: finalize all [K,D] outputs =================
__global__ __launch_bounds__(256) void k_final(const float* __restrict__ ema_w,
                                               const float* __restrict__ ws,
                                               float* __restrict__ out) {
    const int k = blockIdx.x;   // 4096 blocks
    const int d = threadIdx.x;
    const float ntot = ws[WS_NTOT];
    const float ncs  = (ws[WS_NCSRAW + k] + 1e-5f) / (ntot + (float)KDIM * 1e-5f) * ntot;
    const float cnt  = ws[WS_COUNTS + k];
    const float mn   = ws[WS_MEAN + d];
    const float rs   = ws[WS_RSTD + d];
    const size_t e   = (size_t)k * DDIM + d;
    const float dw   = (ws[WS_DWRAW + e] - cnt * mn) * rs;
    const float nw   = ema_w[e] * DECAYV + (1.0f - DECAYV) * dw;
    const float nemb = nw / ncs;
    const float eo   = nemb * sqrtf(ws[WS_NRVAR + d] + EPSV) + ws[WS_NRMEAN + d];
    out[O_EMB + e]  = nemb;
    out[O_EOUT + e] = eo;
    out[O_EMAW + e] = nw;
    if (d == 0) out[O_CS + k] = ncs;
}

// ================= launcher =================
extern "C" void kernel_launch(void* const* d_in, const int* in_sizes, int n_in,
                              void* d_out, int out_size, void* d_ws, size_t ws_size,
                              hipStream_t stream) {
    const float* x     = (const float*)d_in[0];
    const float* emb   = (const float*)d_in[1];
    const float* cs    = (const float*)d_in[2];
    const float* ema_w = (const float*)d_in[3];
    const float* rmean = (const float*)d_in[4];
    const float* rvar  = (const float*)d_in[5];
    float* out = (float*)d_out;
    float* ws  = (float*)d_ws;
    int* idx_int = (int*)(ws + WS_IDX);

    // zero counts + dwraw (contiguous region)
    hipMemsetAsync(ws + WS_COUNTS, 0, (KDIM + (size_t)KDIM * DDIM) * sizeof(float), stream);

    k_bn_partial<<<256, 256, 0, stream>>>(x, ws);
    k_bn_final<<<1, 256, 0, stream>>>(rmean, rvar, ws, out);
    k_eprime<<<KDIM, 256, 0, stream>>>(emb, ws);

    constexpr int LDSB = (2 * 256 * 68 + 64 * 16) * 4 + 64 * 16 * 4;  // 147456 B
    hipFuncSetAttribute((const void*)k_argmin, hipFuncAttributeMaxDynamicSharedMemorySize, LDSB);
    k_argmin<<<1024, 256, LDSB, stream>>>(x, ws, out, idx_int);

    k_scatter<<<2048, 256, 0, stream>>>(x, idx_int, ws);
    k_ema_cs<<<1, 256, 0, stream>>>(cs, ws);
    k_final<<<KDIM, 256, 0, stream>>>(ema_w, ws, out);
}

// Round 2
// 779.963 us; speedup vs baseline: 5.4428x; 5.4428x over previous
//
#include <hip/hip_runtime.h>
#include <cfloat>
#include <cmath>

#define NROWS 65536
#define DDIM 256
#define KDIM 4096

typedef short bf16x8 __attribute__((ext_vector_type(8)));
typedef float f32x4 __attribute__((ext_vector_type(4)));

constexpr float EPSV = 1e-5f;
constexpr float DECAYV = 0.99f;
constexpr float MOMV = 0.1f;
constexpr float DELTA = 3.0f;     // approx-error margin (worst-case 2*eps ~ 1.9)
constexpr int CAP = 16;

// ---------------- workspace layout (float offsets) ----------------
constexpr size_t WS_CNT    = 0;                               // int[NROWS]   (zeroed)
constexpr size_t WS_COUNTS = WS_CNT + NROWS;                  // float[K]     (zeroed)
constexpr size_t WS_DWRAW  = WS_COUNTS + KDIM;                // float[K*D]   (zeroed)
constexpr size_t WS_ZEND   = WS_DWRAW + (size_t)KDIM * DDIM;  // end of zeroed region
constexpr size_t WS_PARTSUM= WS_ZEND;                         // [256][256]
constexpr size_t WS_PARTSQ = WS_PARTSUM + 256 * DDIM;         // [256][256]
constexpr size_t WS_MEAN   = WS_PARTSQ + 256 * DDIM;          // [256]
constexpr size_t WS_RSTD   = WS_MEAN + DDIM;                  // [256]
constexpr size_t WS_NRMEAN = WS_RSTD + DDIM;                  // [256]
constexpr size_t WS_NRVAR  = WS_NRMEAN + DDIM;                // [256]
constexpr size_t WS_BVEC   = WS_NRVAR + DDIM;                 // [4096]
constexpr size_t WS_NCSRAW = WS_BVEC + KDIM;                  // [4096]
constexpr size_t WS_NTOT   = WS_NCSRAW + KDIM;                // [1] + pad
constexpr size_t WS_MMIN   = WS_NTOT + 64;                    // float[NROWS]
constexpr size_t WS_IDX    = WS_MMIN + NROWS;                 // int[NROWS]
constexpr size_t WS_CAND   = WS_IDX + NROWS;                  // int[NROWS*CAP]
constexpr size_t WS_EPROW  = WS_CAND + (size_t)NROWS * CAP;   // float[K][D] row-major e'
constexpr size_t WS_EHP    = WS_EPROW + (size_t)KDIM * DDIM;  // bf16 image, 2 MB (524288 floats)
constexpr size_t WS_TOTALF = WS_EHP + 524288;                 // ~16 MB

// ---------------- output layout (float offsets) ----------------
constexpr size_t O_IDX   = 0;
constexpr size_t O_EMB   = NROWS;
constexpr size_t O_EOUT  = O_EMB + (size_t)KDIM * DDIM;
constexpr size_t O_CS    = O_EOUT + (size_t)KDIM * DDIM;
constexpr size_t O_EMAW  = O_CS + KDIM;
constexpr size_t O_RMEAN = O_EMAW + (size_t)KDIM * DDIM;
constexpr size_t O_RVAR  = O_RMEAN + DDIM;

__device__ inline unsigned bfpack(float a, float b) {   // RNE f32->bf16 pair
    unsigned ua = __float_as_uint(a), ub = __float_as_uint(b);
    ua = (ua + 0x7FFFu + ((ua >> 16) & 1u)) >> 16;
    ub = (ub + 0x7FFFu + ((ub >> 16) & 1u)) & 0xFFFF0000u;
    return (ua & 0xFFFFu) | ub;
}

#define GLOAD_LDS16(g, l) __builtin_amdgcn_global_load_lds(                       \
        (const __attribute__((address_space(1))) void*)(g),                        \
        (__attribute__((address_space(3))) void*)(l), 16, 0, 0)

// ================= K1: per-block column sums =================
__global__ __launch_bounds__(256) void k_bn_partial(const float* __restrict__ x,
                                                    float* __restrict__ ws) {
    const int d = threadIdx.x;
    const int b = blockIdx.x;
    float s = 0.f, sq = 0.f;
    for (int r = b; r < NROWS; r += 256) {
        const float v = x[(size_t)r * DDIM + d];
        s += v; sq += v * v;
    }
    ws[WS_PARTSUM + (size_t)b * DDIM + d] = s;
    ws[WS_PARTSQ  + (size_t)b * DDIM + d] = sq;
}

// ================= K2: finalize BN stats =================
__global__ __launch_bounds__(256) void k_bn_final(const float* __restrict__ rmean_in,
                                                  const float* __restrict__ rvar_in,
                                                  float* __restrict__ ws,
                                                  float* __restrict__ out) {
    const int d = threadIdx.x;
    float s = 0.f, sq = 0.f;
    for (int b = 0; b < 256; ++b) {
        s  += ws[WS_PARTSUM + (size_t)b * DDIM + d];
        sq += ws[WS_PARTSQ  + (size_t)b * DDIM + d];
    }
    const float mean = s / (float)NROWS;
    float var = sq / (float)NROWS - mean * mean;
    var = fmaxf(var, 0.f);
    const float rstd = 1.0f / sqrtf(var + EPSV);
    const float nrm  = (1.0f - MOMV) * rmean_in[d] + MOMV * mean;
    const float varu = var * ((float)NROWS / (float)(NROWS - 1));
    const float nrv  = (1.0f - MOMV) * rvar_in[d] + MOMV * varu;
    ws[WS_MEAN + d] = mean;
    ws[WS_RSTD + d] = rstd;
    ws[WS_NRMEAN + d] = nrm;
    ws[WS_NRVAR + d] = nrv;
    out[O_RMEAN + d] = nrm;
    out[O_RVAR + d] = nrv;
}

// ================= K3: e' fp32 rows + bf16 rotated image + b_k =================
__global__ __launch_bounds__(128) void k_eprime(const float* __restrict__ emb,
                                                float* __restrict__ ws) {
    __shared__ float red[128];
    const int k = blockIdx.x, t = threadIdx.x;
    const int d0 = 2 * t, d1 = 2 * t + 1;
    const float em0 = emb[(size_t)k * DDIM + d0], em1 = emb[(size_t)k * DDIM + d1];
    const float rs0 = ws[WS_RSTD + d0], rs1 = ws[WS_RSTD + d1];
    const float mn0 = ws[WS_MEAN + d0], mn1 = ws[WS_MEAN + d1];
    const float e0 = em0 * rs0, e1 = em1 * rs1;
    ws[WS_EPROW + (size_t)k * DDIM + d0] = e0;
    ws[WS_EPROW + (size_t)k * DDIM + d1] = e1;
    // packed bf16 image: [chunk=k>>7][col=k&127][512B row, rotated by (col&15)<<5]
    char* img = (char*)(ws + WS_EHP);
    const int c = k & 127;
    const int db = (4 * t + ((c & 15) << 5)) & 511;
    *(unsigned*)(img + (size_t)(k >> 7) * 65536 + (size_t)c * 512 + db) = bfpack(e0, e1);
    red[t] = em0 * em0 + 2.f * mn0 * e0 + em1 * em1 + 2.f * mn1 * e1;
    __syncthreads();
    for (int s = 64; s > 0; s >>= 1) { if (t < s) red[t] += red[t + s]; __syncthreads(); }
    if (t == 0) ws[WS_BVEC + k] = red[0];
}

// ================= K4: bf16 MFMA GEMM (pass1: row-min; pass2: candidate append) ====
// block: 128 rows x 4096 cols in 32 chunks of 128. 4 waves (2x2), wave tile 64x64.
// LDS: Ximg 64KB + Eimg 64KB + rowred 1KB. d-major bf16 rows of 512B, rotated by
// ((idx&15)<<5) so 16x16x32 fragment reads are <=2-way bank aliased (free).
template<int PHASE>
__global__ __launch_bounds__(256) void k_gemm(const float* __restrict__ x,
                                              float* __restrict__ ws) {
    extern __shared__ char smem[];
    char* Ximg = smem;
    char* Eimg = smem + 65536;
    float* rowred = (float*)(smem + 131072);  // [128][2]

    const int t = threadIdx.x;
    const int lane = t & 63, wid = t >> 6;
    const int wr = wid >> 1, wc = wid & 1;
    const int l4 = lane & 15, kg = lane >> 4;
    const int rowbase = blockIdx.x * 128;

    // ---- stage X tile: fp32 -> bf16 rotated image (once per block) ----
    const float4* xg = (const float4*)(x + (size_t)rowbase * DDIM);
#pragma unroll 8
    for (int i = 0; i < 32; ++i) {
        const int q = t + i * 256;          // float4 index over [128 rows][64 quads]
        const int row = q >> 6, dq = q & 63;
        const float4 v = xg[q];
        const unsigned w0 = bfpack(v.x, v.y), w1 = bfpack(v.z, v.w);
        const int db = (8 * dq + ((row & 15) << 5)) & 511;
        *(uint2*)(Ximg + row * 512 + db) = make_uint2(w0, w1);
    }

    const float* bvec = ws + WS_BVEC;
    const char* ehp = (const char*)(ws + WS_EHP);
    int* cnt  = (int*)(ws + WS_CNT);
    int* cand = (int*)(ws + WS_CAND);
    float* mmin = ws + WS_MMIN;

    float best[4][4];
    float mreg[4][4];
    if (PHASE == 1) {
#pragma unroll
        for (int m = 0; m < 4; ++m)
#pragma unroll
            for (int r = 0; r < 4; ++r) best[m][r] = FLT_MAX;
    } else {
#pragma unroll
        for (int m = 0; m < 4; ++m)
#pragma unroll
            for (int r = 0; r < 4; ++r)
                mreg[m][r] = ws[WS_MMIN + rowbase + wr * 64 + m * 16 + kg * 4 + r] + DELTA;
    }

    for (int ch = 0; ch < 32; ++ch) {
        __syncthreads();  // previous-chunk reads (and X-stage writes) complete
        // async-stage E chunk (pre-packed image -> straight contiguous copy)
#pragma unroll
        for (int it = 0; it < 16; ++it) {
            const int off = (it * 4 + wid) * 1024;
            GLOAD_LDS16(ehp + (size_t)ch * 65536 + off + lane * 16, Eimg + off);
        }
        __syncthreads();  // drains vmcnt: E ready

        f32x4 acc[4][4];
#pragma unroll
        for (int m = 0; m < 4; ++m)
#pragma unroll
            for (int n = 0; n < 4; ++n) acc[m][n] = 0.f;

#pragma unroll 2
        for (int ts = 0; ts < 8; ++ts) {
            const int rot = (64 * ts + 16 * kg + (l4 << 5)) & 511;
            bf16x8 a[4], b[4];
#pragma unroll
            for (int m = 0; m < 4; ++m)
                a[m] = *(const bf16x8*)(Ximg + (wr * 64 + m * 16 + l4) * 512 + rot);
#pragma unroll
            for (int n = 0; n < 4; ++n)
                b[n] = *(const bf16x8*)(Eimg + (wc * 64 + n * 16 + l4) * 512 + rot);
#pragma unroll
            for (int m = 0; m < 4; ++m)
#pragma unroll
                for (int n = 0; n < 4; ++n)
                    acc[m][n] = __builtin_amdgcn_mfma_f32_16x16x32_bf16(a[m], b[n], acc[m][n], 0, 0, 0);
        }

        float bc[4];
#pragma unroll
        for (int n = 0; n < 4; ++n) bc[n] = bvec[ch * 128 + wc * 64 + n * 16 + l4];

        if (PHASE == 1) {
#pragma unroll
            for (int m = 0; m < 4; ++m)
#pragma unroll
                for (int n = 0; n < 4; ++n)
#pragma unroll
                    for (int r = 0; r < 4; ++r) {
                        const float s = fmaf(-2.f, acc[m][n][r], bc[n]);
                        best[m][r] = fminf(best[m][r], s);
                    }
        } else {
#pragma unroll
            for (int m = 0; m < 4; ++m)
#pragma unroll
                for (int n = 0; n < 4; ++n)
#pragma unroll
                    for (int r = 0; r < 4; ++r) {
                        const float s = fmaf(-2.f, acc[m][n][r], bc[n]);
                        if (s <= mreg[m][r]) {
                            const int row = rowbase + wr * 64 + m * 16 + kg * 4 + r;
                            const int k = ch * 128 + wc * 64 + n * 16 + l4;
                            const int pos = atomicAdd(&cnt[row], 1);
                            if (pos < CAP) cand[(size_t)row * CAP + pos] = k;
                        }
                    }
        }
    }

    if (PHASE == 1) {
        // fold cols: min over the 16 lanes (l4) holding each row
#pragma unroll
        for (int m = 0; m < 4; ++m)
#pragma unroll
            for (int r = 0; r < 4; ++r) {
                float v = best[m][r];
                v = fminf(v, __shfl_xor(v, 1));
                v = fminf(v, __shfl_xor(v, 2));
                v = fminf(v, __shfl_xor(v, 4));
                v = fminf(v, __shfl_xor(v, 8));
                if (l4 == 0) rowred[(wr * 64 + m * 16 + kg * 4 + r) * 2 + wc] = v;
            }
        __syncthreads();
        if (t < 128) mmin[rowbase + t] = fminf(rowred[t * 2], rowred[t * 2 + 1]);
    }
}

// ================= K5: exact fp32 resolve of candidates (1 wave/row) ============
__global__ __launch_bounds__(256) void k_resolve(const float* __restrict__ x,
                                                 const float* __restrict__ ws,
                                                 float* __restrict__ out,
                                                 int* __restrict__ idx_int,
                                                 const int* __restrict__ cnt,
                                                 const int* __restrict__ cand) {
    const int t = threadIdx.x, lane = t & 63, w = t >> 6;
    const int row = blockIdx.x * 4 + w;
    const float* eprow = ws + WS_EPROW;
    const float* bvec = ws + WS_BVEC;
    const float4 xr = ((const float4*)(x + (size_t)row * DDIM))[lane];
    const int n = cnt[row];
    float bestv = FLT_MAX;
    int bestk = KDIM;
    if (n >= 1 && n <= CAP) {
        for (int c = 0; c < n; ++c) {
            const int k = cand[(size_t)row * CAP + c];
            const float4 er = ((const float4*)(eprow + (size_t)k * DDIM))[lane];
            float p = xr.x * er.x + xr.y * er.y + xr.z * er.z + xr.w * er.w;
            p += __shfl_xor(p, 32); p += __shfl_xor(p, 16); p += __shfl_xor(p, 8);
            p += __shfl_xor(p, 4);  p += __shfl_xor(p, 2);  p += __shfl_xor(p, 1);
            const float s = fmaf(-2.f, p, bvec[k]);
            if (s < bestv || (s == bestv && k < bestk)) { bestv = s; bestk = k; }
        }
    } else {  // overflow / safety fallback: exact full scan (practically never runs)
        for (int k = 0; k < KDIM; ++k) {
            const float4 er = ((const float4*)(eprow + (size_t)k * DDIM))[lane];
            float p = xr.x * er.x + xr.y * er.y + xr.z * er.z + xr.w * er.w;
            p += __shfl_xor(p, 32); p += __shfl_xor(p, 16); p += __shfl_xor(p, 8);
            p += __shfl_xor(p, 4);  p += __shfl_xor(p, 2);  p += __shfl_xor(p, 1);
            const float s = fmaf(-2.f, p, bvec[k]);
            if (s < bestv || (s == bestv && k < bestk)) { bestv = s; bestk = k; }
        }
    }
    if (lane == 0) { out[O_IDX + row] = (float)bestk; idx_int[row] = bestk; }
}

// ================= K6: scatter raw-x sums + counts =================
__global__ __launch_bounds__(256) void k_scatter(const float* __restrict__ x,
                                                 const int* __restrict__ idx_int,
                                                 float* __restrict__ ws) {
    float* counts = ws + WS_COUNTS;
    float* dwraw  = ws + WS_DWRAW;
    const int t = threadIdx.x;
    for (int r = blockIdx.x; r < NROWS; r += gridDim.x) {
        const int k = idx_int[r];
        atomicAdd(&dwraw[(size_t)k * DDIM + t], x[(size_t)r * DDIM + t]);
        if (t == 0) atomicAdd(&counts[k], 1.0f);
    }
}

// ================= K7a: EMA cluster size + n_total =================
__global__ __launch_bounds__(256) void k_ema_cs(const float* __restrict__ cs_in,
                                                float* __restrict__ ws) {
    __shared__ float red[256];
    const int t = threadIdx.x;
    float part = 0.f;
    for (int k = t; k < KDIM; k += 256) {
        const float ncs = cs_in[k] * DECAYV + (1.0f - DECAYV) * ws[WS_COUNTS + k];
        ws[WS_NCSRAW + k] = ncs;
        part += ncs;
    }
    red[t] = part;
    __syncthreads();
    for (int s = 128; s > 0; s >>= 1) { if (t < s) red[t] += red[t + s]; __syncthreads(); }
    if (t == 0) ws[WS_NTOT] = red[0];
}

// ================= K7b: finalize [K,D] outputs =================
__global__ __launch_bounds__(256) void k_final(const float* __restrict__ ema_w,
                                               const float* __restrict__ ws,
                                               float* __restrict__ out) {
    const int k = blockIdx.x;
    const int d = threadIdx.x;
    const float ntot = ws[WS_NTOT];
    const float ncs  = (ws[WS_NCSRAW + k] + 1e-5f) / (ntot + (float)KDIM * 1e-5f) * ntot;
    const float cnt  = ws[WS_COUNTS + k];
    const float mn   = ws[WS_MEAN + d];
    const float rs   = ws[WS_RSTD + d];
    const size_t e   = (size_t)k * DDIM + d;
    const float dw   = (ws[WS_DWRAW + e] - cnt * mn) * rs;
    const float nw   = ema_w[e] * DECAYV + (1.0f - DECAYV) * dw;
    const float nemb = nw / ncs;
    const float eo   = nemb * sqrtf(ws[WS_NRVAR + d] + EPSV) + ws[WS_NRMEAN + d];
    out[O_EMB + e]  = nemb;
    out[O_EOUT + e] = eo;
    out[O_EMAW + e] = nw;
    if (d == 0) out[O_CS + k] = ncs;
}

// ================= launcher =================
extern "C" void kernel_launch(void* const* d_in, const int* in_sizes, int n_in,
                              void* d_out, int out_size, void* d_ws, size_t ws_size,
                              hipStream_t stream) {
    const float* x     = (const float*)d_in[0];
    const float* emb   = (const float*)d_in[1];
    const float* cs    = (const float*)d_in[2];
    const float* ema_w = (const float*)d_in[3];
    const float* rmean = (const float*)d_in[4];
    const float* rvar  = (const float*)d_in[5];
    float* out = (float*)d_out;
    float* ws  = (float*)d_ws;

    // zero cnt + counts + dwraw (contiguous region at ws base)
    hipMemsetAsync(ws + WS_CNT, 0, WS_ZEND * sizeof(float), stream);

    k_bn_partial<<<256, 256, 0, stream>>>(x, ws);
    k_bn_final<<<1, 256, 0, stream>>>(rmean, rvar, ws, out);
    k_eprime<<<KDIM, 128, 0, stream>>>(emb, ws);

    constexpr int LDSB = 65536 + 65536 + 1024;  // 132096 B
    hipFuncSetAttribute(reinterpret_cast<const void*>(&k_gemm<1>),
                        hipFuncAttributeMaxDynamicSharedMemorySize, LDSB);
    hipFuncSetAttribute(reinterpret_cast<const void*>(&k_gemm<2>),
                        hipFuncAttributeMaxDynamicSharedMemorySize, LDSB);
    k_gemm<1><<<512, 256, LDSB, stream>>>(x, ws);
    k_gemm<2><<<512, 256, LDSB, stream>>>(x, ws);

    k_resolve<<<NROWS / 4, 256, 0, stream>>>(x, ws, out, (int*)(ws + WS_IDX),
                                             (const int*)(ws + WS_CNT),
                                             (const int*)(ws + WS_CAND));
    k_scatter<<<2048, 256, 0, stream>>>(x, (const int*)(ws + WS_IDX), ws);
    k_ema_cs<<<1, 256, 0, stream>>>(cs, ws);
    k_final<<<KDIM, 256, 0, stream>>>(ema_w, ws, out);
}

// Round 3
// 589.327 us; speedup vs baseline: 7.2035x; 1.3235x over previous
//
#include <hip/hip_runtime.h>
#include <cfloat>
#include <cmath>

#define NROWS 65536
#define DDIM 256
#define KDIM 4096

typedef short bf16x8 __attribute__((ext_vector_type(8)));
typedef float f32x4 __attribute__((ext_vector_type(4)));

constexpr float EPSV = 1e-5f;
constexpr float DECAYV = 0.99f;
constexpr float MOMV = 0.1f;
constexpr float DELTA = 2.0f;   // bf16 dot err (<~0.5 realistic worst) + 2x0.25 pack quant
constexpr int CAP = 16;

// ---------------- workspace layout (float offsets) ----------------
constexpr size_t WS_CNT     = 0;                                  // int[N] cand counts (zeroed)
constexpr size_t WS_NFLAG   = WS_CNT + NROWS;                     // int[1] (+pad, zeroed)
constexpr size_t WS_COUNTS  = WS_NFLAG + 64;                      // float[K] (zeroed)
constexpr size_t WS_DWRAW   = WS_COUNTS + KDIM;                   // float[K*D] (zeroed)
constexpr size_t WS_ZEND    = WS_DWRAW + (size_t)KDIM * DDIM;     // end of zeroed region
constexpr size_t WS_PARTSUM = WS_ZEND;                            // [256][256]
constexpr size_t WS_PARTSQ  = WS_PARTSUM + 256 * DDIM;            // [256][256]
constexpr size_t WS_MEAN    = WS_PARTSQ + 256 * DDIM;             // [256]
constexpr size_t WS_RSTD    = WS_MEAN + DDIM;                     // [256]
constexpr size_t WS_NRMEAN  = WS_RSTD + DDIM;                     // [256]
constexpr size_t WS_NRVAR   = WS_NRMEAN + DDIM;                   // [256]
constexpr size_t WS_BVEC    = WS_NRVAR + DDIM;                    // [4096]
constexpr size_t WS_NCSRAW  = WS_BVEC + KDIM;                     // [4096]
constexpr size_t WS_NTOT    = WS_NCSRAW + KDIM;                   // [1] + pad
constexpr size_t WS_ROWINFO = WS_NTOT + 64;                       // uint2[N]
constexpr size_t WS_IDX     = WS_ROWINFO + 2 * (size_t)NROWS;     // int[N]
constexpr size_t WS_ROWTHR  = WS_IDX + NROWS;                     // float[N]
constexpr size_t WS_FLAG    = WS_ROWTHR + NROWS;                  // int[N]
constexpr size_t WS_CAND    = WS_FLAG + NROWS;                    // int[N*CAP]
constexpr size_t WS_EPROW   = WS_CAND + (size_t)NROWS * CAP;      // float[K][D] e' rows
constexpr size_t WS_EIMG    = WS_EPROW + (size_t)KDIM * DDIM;     // bf16 E image 2MB
constexpr size_t WS_XIMG    = WS_EIMG + 524288;                   // bf16 X image 32MB

// ---------------- output layout (float offsets) ----------------
constexpr size_t O_IDX   = 0;
constexpr size_t O_EMB   = NROWS;
constexpr size_t O_EOUT  = O_EMB + (size_t)KDIM * DDIM;
constexpr size_t O_CS    = O_EOUT + (size_t)KDIM * DDIM;
constexpr size_t O_EMAW  = O_CS + KDIM;
constexpr size_t O_RMEAN = O_EMAW + (size_t)KDIM * DDIM;
constexpr size_t O_RVAR  = O_RMEAN + DDIM;

__device__ inline unsigned bfpack(float a, float b) {   // RNE f32->bf16 pair
    unsigned ua = __float_as_uint(a), ub = __float_as_uint(b);
    ua = (ua + 0x7FFFu + ((ua >> 16) & 1u)) >> 16;
    ub = (ub + 0x7FFFu + ((ub >> 16) & 1u)) & 0xFFFF0000u;
    return (ua & 0xFFFFu) | ub;
}
__device__ inline unsigned umn(unsigned a, unsigned b) { return a < b ? a : b; }
__device__ inline unsigned umx(unsigned a, unsigned b) { return a > b ? a : b; }

#define GLOAD_LDS16(g, l) __builtin_amdgcn_global_load_lds(                       \
        (const __attribute__((address_space(1))) void*)(g),                        \
        (__attribute__((address_space(3))) void*)(l), 16, 0, 0)

// ===== K1: BN partial sums + fused x -> bf16 rotated image =====
__global__ __launch_bounds__(128) void k_bnpack(const float* __restrict__ x,
                                                float* __restrict__ ws) {
    const int t = threadIdx.x;      // d-pair 0..127
    const int b = blockIdx.x;       // 256
    char* ximg = (char*)(ws + WS_XIMG);
    float s0 = 0.f, s1 = 0.f, q0 = 0.f, q1 = 0.f;
    for (int r = b; r < NROWS; r += 256) {
        const float2 v = *(const float2*)(x + (size_t)r * DDIM + 2 * t);
        s0 += v.x; s1 += v.y; q0 += v.x * v.x; q1 += v.y * v.y;
        const int db = (4 * t + ((r & 15) << 5)) & 511;
        *(unsigned*)(ximg + (size_t)r * 512 + db) = bfpack(v.x, v.y);
    }
    *(float2*)(ws + WS_PARTSUM + (size_t)b * DDIM + 2 * t) = make_float2(s0, s1);
    *(float2*)(ws + WS_PARTSQ  + (size_t)b * DDIM + 2 * t) = make_float2(q0, q1);
}

// ===== K2: finalize BN stats =====
__global__ __launch_bounds__(256) void k_bn_final(const float* __restrict__ rmean_in,
                                                  const float* __restrict__ rvar_in,
                                                  float* __restrict__ ws,
                                                  float* __restrict__ out) {
    const int d = threadIdx.x;
    float s = 0.f, sq = 0.f;
    for (int b = 0; b < 256; ++b) {
        s  += ws[WS_PARTSUM + (size_t)b * DDIM + d];
        sq += ws[WS_PARTSQ  + (size_t)b * DDIM + d];
    }
    const float mean = s / (float)NROWS;
    float var = sq / (float)NROWS - mean * mean;
    var = fmaxf(var, 0.f);
    const float rstd = 1.0f / sqrtf(var + EPSV);
    const float nrm  = (1.0f - MOMV) * rmean_in[d] + MOMV * mean;
    const float varu = var * ((float)NROWS / (float)(NROWS - 1));
    const float nrv  = (1.0f - MOMV) * rvar_in[d] + MOMV * varu;
    ws[WS_MEAN + d] = mean;
    ws[WS_RSTD + d] = rstd;
    ws[WS_NRMEAN + d] = nrm;
    ws[WS_NRVAR + d] = nrv;
    out[O_RMEAN + d] = nrm;
    out[O_RVAR + d] = nrv;
}

// ===== K3: e' fp32 rows + bf16 rotated image + b_k =====
__global__ __launch_bounds__(128) void k_eprime(const float* __restrict__ emb,
                                                float* __restrict__ ws) {
    __shared__ float red[128];
    const int k = blockIdx.x, t = threadIdx.x;
    const int d0 = 2 * t, d1 = 2 * t + 1;
    const float em0 = emb[(size_t)k * DDIM + d0], em1 = emb[(size_t)k * DDIM + d1];
    const float rs0 = ws[WS_RSTD + d0], rs1 = ws[WS_RSTD + d1];
    const float mn0 = ws[WS_MEAN + d0], mn1 = ws[WS_MEAN + d1];
    const float e0 = em0 * rs0, e1 = em1 * rs1;
    ws[WS_EPROW + (size_t)k * DDIM + d0] = e0;
    ws[WS_EPROW + (size_t)k * DDIM + d1] = e1;
    char* img = (char*)(ws + WS_EIMG);
    const int db = (4 * t + ((k & 15) << 5)) & 511;
    *(unsigned*)(img + (size_t)k * 512 + db) = bfpack(e0, e1);
    red[t] = em0 * em0 + 2.f * mn0 * e0 + em1 * em1 + 2.f * mn1 * e1;
    __syncthreads();
    for (int s = 64; s > 0; s >>= 1) { if (t < s) red[t] += red[t + s]; __syncthreads(); }
    if (t == 0) ws[WS_BVEC + k] = red[0];
}

// ===== K4: single-pass MFMA GEMM with packed top-2 tracking =====
// 512 blocks x 4 waves; wave owns 32 private rows (A-frags in 64 VGPR).
// LDS: E-chunk double-buffer 2x32KB -> 2 blocks/CU (2 waves/SIMD).
__global__ __launch_bounds__(256, 2) void k_gemm_min(float* __restrict__ ws) {
    extern __shared__ char smem[];      // 2 x 32768
    const int t = threadIdx.x, lane = t & 63, w = t >> 6;
    const int l4 = lane & 15, kg = lane >> 4;
    const int rowbase = blockIdx.x * 128 + w * 32;
    const char* ximg = (const char*)(ws + WS_XIMG);
    const char* eimg = (const char*)(ws + WS_EIMG);
    const float* bvec = ws + WS_BVEC;

    // A fragments: rows rowbase + m*16 + l4, all 8 k-steps (rotated image)
    bf16x8 a[2][8];
#pragma unroll
    for (int m = 0; m < 2; ++m) {
        const int row = rowbase + m * 16 + l4;
        const char* rp = ximg + (size_t)row * 512;
#pragma unroll
        for (int ts = 0; ts < 8; ++ts) {
            const int byte = ((kg * 16 + ts * 64) + (l4 << 5)) & 511;
            a[m][ts] = *(const bf16x8*)(rp + byte);
        }
    }

    unsigned b1p[2][4], b2p[2][4];
#pragma unroll
    for (int m = 0; m < 2; ++m)
#pragma unroll
        for (int r = 0; r < 4; ++r) { b1p[m][r] = 0xFFFFFFFFu; b2p[m][r] = 0xFFFFFFFFu; }

    // prologue: stage chunk 0
#pragma unroll
    for (int rr = 0; rr < 8; ++rr) {
        const int off = rr * 4096 + w * 1024;
        GLOAD_LDS16(eimg + off + lane * 16, smem + off);
    }
    __syncthreads();

    for (int ch = 0; ch < 64; ++ch) {
        const char* cur = smem + (ch & 1) * 32768;
        if (ch + 1 < 64) {            // prefetch next chunk into other buffer
            const char* src = eimg + (size_t)(ch + 1) * 32768;
            char* nb = smem + ((ch + 1) & 1) * 32768;
#pragma unroll
            for (int rr = 0; rr < 8; ++rr) {
                const int off = rr * 4096 + w * 1024;
                GLOAD_LDS16(src + off + lane * 16, nb + off);
            }
        }

        f32x4 acc[2][4];
#pragma unroll
        for (int m = 0; m < 2; ++m)
#pragma unroll
            for (int n = 0; n < 4; ++n) acc[m][n] = 0.f;

#pragma unroll
        for (int ts = 0; ts < 8; ++ts) {
            const int rot = ((kg * 16 + ts * 64) + (l4 << 5)) & 511;
            bf16x8 bfr[4];
#pragma unroll
            for (int n = 0; n < 4; ++n)
                bfr[n] = *(const bf16x8*)(cur + (n * 16 + l4) * 512 + rot);
#pragma unroll
            for (int m = 0; m < 2; ++m)
#pragma unroll
                for (int n = 0; n < 4; ++n)
                    acc[m][n] = __builtin_amdgcn_mfma_f32_16x16x32_bf16(a[m][ts], bfr[n], acc[m][n], 0, 0, 0);
        }

        // epilogue: packed (value | col) exact top-2 update
#pragma unroll
        for (int n = 0; n < 4; ++n) {
            const int col = ch * 64 + n * 16 + l4;
            const float bc = bvec[col];
#pragma unroll
            for (int m = 0; m < 2; ++m)
#pragma unroll
                for (int r = 0; r < 4; ++r) {
                    const float s = fmaxf(fmaf(-2.f, acc[m][n][r], bc), 0.f);
                    const unsigned p = (__float_as_uint(s) & 0xFFFFF000u) | (unsigned)col;
                    const unsigned t1 = umn(p, b1p[m][r]);
                    b2p[m][r] = umn(umx(p, b1p[m][r]), b2p[m][r]);
                    b1p[m][r] = t1;
                }
        }
        __syncthreads();   // drains prefetch (vmcnt0) + everyone done with cur
    }

    // merge top-2 across the 16 l4-lanes holding each row
    uint2* rowinfo = (uint2*)(ws + WS_ROWINFO);
#pragma unroll
    for (int m = 0; m < 2; ++m)
#pragma unroll
        for (int r = 0; r < 4; ++r) {
            unsigned v1 = b1p[m][r], v2 = b2p[m][r];
#pragma unroll
            for (int st = 1; st < 16; st <<= 1) {
                const unsigned o1 = (unsigned)__shfl_xor((int)v1, st);
                const unsigned o2 = (unsigned)__shfl_xor((int)v2, st);
                v2 = umn(umx(v1, o1), umn(v2, o2));
                v1 = umn(v1, o1);
            }
            if (l4 == 0)
                rowinfo[rowbase + m * 16 + kg * 4 + r] = make_uint2(v1, v2);
        }
}

// ===== K5: flag close rows; decide clear rows =====
__global__ __launch_bounds__(256) void k_flag(float* __restrict__ ws,
                                              float* __restrict__ out) {
    const int r = blockIdx.x * 256 + threadIdx.x;
    const uint2 bi = ((const uint2*)(ws + WS_ROWINFO))[r];
    const float b1v = __uint_as_float(bi.x & 0xFFFFF000u);
    const float b2v = __uint_as_float(bi.y & 0xFFFFF000u);
    const int i1 = (int)(bi.x & 0xFFFu);
    ws[WS_ROWTHR + r] = b1v + DELTA;
    if (b2v <= b1v + DELTA) {
        const int pos = atomicAdd((int*)(ws + WS_NFLAG), 1);
        ((int*)(ws + WS_FLAG))[pos] = r;
    } else {
        out[O_IDX + r] = (float)i1;
        ((int*)(ws + WS_IDX))[r] = i1;
    }
}

// ===== K6: candidate-append mini-GEMM over flagged rows only =====
__global__ __launch_bounds__(256, 2) void k_cand(float* __restrict__ ws) {
    extern __shared__ char smem[];
    const int t = threadIdx.x, lane = t & 63, w = t >> 6;
    const int l4 = lane & 15, kg = lane >> 4;
    const char* ximg = (const char*)(ws + WS_XIMG);
    const char* eimg = (const char*)(ws + WS_EIMG);
    const float* bvec = ws + WS_BVEC;
    const int* flag = (const int*)(ws + WS_FLAG);
    int* cnt = (int*)(ws + WS_CNT);
    int* cand = (int*)(ws + WS_CAND);
    const int nflag = *(const int*)(ws + WS_NFLAG);
    if (nflag == 0) return;
    const int ntiles = (nflag + 127) >> 7;

    for (int tile = blockIdx.x; tile < ntiles; tile += gridDim.x) {
        const int base = tile * 128 + w * 32;
        bf16x8 a[2][8];
        int frow[2][4];
        float thr[2][4];
#pragma unroll
        for (int m = 0; m < 2; ++m) {
            const int ia = base + m * 16 + l4;
            const int rowa = flag[ia < nflag ? ia : (nflag - 1)];
            const char* rp = ximg + (size_t)rowa * 512;
#pragma unroll
            for (int ts = 0; ts < 8; ++ts) {
                const int byte = ((kg * 16 + ts * 64) + ((rowa & 15) << 5)) & 511;
                a[m][ts] = *(const bf16x8*)(rp + byte);
            }
#pragma unroll
            for (int r = 0; r < 4; ++r) {
                const int ie = base + m * 16 + kg * 4 + r;
                const bool val = ie < nflag;
                const int rowe = flag[val ? ie : (nflag - 1)];
                frow[m][r] = rowe;
                thr[m][r] = val ? ws[WS_ROWTHR + rowe] : -1e30f;
            }
        }
#pragma unroll
        for (int rr = 0; rr < 8; ++rr) {
            const int off = rr * 4096 + w * 1024;
            GLOAD_LDS16(eimg + off + lane * 16, smem + off);
        }
        __syncthreads();

        for (int ch = 0; ch < 64; ++ch) {
            const char* cur = smem + (ch & 1) * 32768;
            if (ch + 1 < 64) {
                const char* src = eimg + (size_t)(ch + 1) * 32768;
                char* nb = smem + ((ch + 1) & 1) * 32768;
#pragma unroll
                for (int rr = 0; rr < 8; ++rr) {
                    const int off = rr * 4096 + w * 1024;
                    GLOAD_LDS16(src + off + lane * 16, nb + off);
                }
            }
            f32x4 acc[2][4];
#pragma unroll
            for (int m = 0; m < 2; ++m)
#pragma unroll
                for (int n = 0; n < 4; ++n) acc[m][n] = 0.f;
#pragma unroll
            for (int ts = 0; ts < 8; ++ts) {
                const int rot = ((kg * 16 + ts * 64) + (l4 << 5)) & 511;
                bf16x8 bfr[4];
#pragma unroll
                for (int n = 0; n < 4; ++n)
                    bfr[n] = *(const bf16x8*)(cur + (n * 16 + l4) * 512 + rot);
#pragma unroll
                for (int m = 0; m < 2; ++m)
#pragma unroll
                    for (int n = 0; n < 4; ++n)
                        acc[m][n] = __builtin_amdgcn_mfma_f32_16x16x32_bf16(a[m][ts], bfr[n], acc[m][n], 0, 0, 0);
            }
#pragma unroll
            for (int n = 0; n < 4; ++n) {
                const int col = ch * 64 + n * 16 + l4;
                const float bc = bvec[col];
#pragma unroll
                for (int m = 0; m < 2; ++m)
#pragma unroll
                    for (int r = 0; r < 4; ++r) {
                        const float s = fmaf(-2.f, acc[m][n][r], bc);
                        if (s <= thr[m][r]) {
                            const int rr2 = frow[m][r];
                            const int pos = atomicAdd(&cnt[rr2], 1);
                            if (pos < CAP) cand[(size_t)rr2 * CAP + pos] = col;
                        }
                    }
            }
            __syncthreads();
        }
    }
}

// ===== K7: exact fp32 resolve for flagged rows =====
__global__ __launch_bounds__(256) void k_resolve_f(const float* __restrict__ x,
                                                   float* __restrict__ ws,
                                                   float* __restrict__ out) {
    const int t = threadIdx.x, lane = t & 63;
    const int gw = (blockIdx.x * 256 + t) >> 6;     // 1024 waves
    const int nflag = *(const int*)(ws + WS_NFLAG);
    const int* flag = (const int*)(ws + WS_FLAG);
    const int* cnt = (const int*)(ws + WS_CNT);
    const int* cand = (const int*)(ws + WS_CAND);
    const float* eprow = ws + WS_EPROW;
    const float* bvec = ws + WS_BVEC;
    int* idx_int = (int*)(ws + WS_IDX);
    for (int i = gw; i < nflag; i += 1024) {
        const int row = flag[i];
        const float4 xr = ((const float4*)(x + (size_t)row * DDIM))[lane];
        const int n = cnt[row];
        float bestv = FLT_MAX;
        int bestk = KDIM;
        if (n >= 1 && n <= CAP) {
            for (int c = 0; c < n; ++c) {
                const int k = cand[(size_t)row * CAP + c];
                const float4 er = ((const float4*)(eprow + (size_t)k * DDIM))[lane];
                float p = xr.x * er.x + xr.y * er.y + xr.z * er.z + xr.w * er.w;
                p += __shfl_xor(p, 32); p += __shfl_xor(p, 16); p += __shfl_xor(p, 8);
                p += __shfl_xor(p, 4);  p += __shfl_xor(p, 2);  p += __shfl_xor(p, 1);
                const float s = fmaf(-2.f, p, bvec[k]);
                if (s < bestv || (s == bestv && k < bestk)) { bestv = s; bestk = k; }
            }
        } else {   // overflow / safety fallback: exact full scan
            for (int k = 0; k < KDIM; ++k) {
                const float4 er = ((const float4*)(eprow + (size_t)k * DDIM))[lane];
                float p = xr.x * er.x + xr.y * er.y + xr.z * er.z + xr.w * er.w;
                p += __shfl_xor(p, 32); p += __shfl_xor(p, 16); p += __shfl_xor(p, 8);
                p += __shfl_xor(p, 4);  p += __shfl_xor(p, 2);  p += __shfl_xor(p, 1);
                const float s = fmaf(-2.f, p, bvec[k]);
                if (s < bestv || (s == bestv && k < bestk)) { bestv = s; bestk = k; }
            }
        }
        if (lane == 0) { out[O_IDX + row] = (float)bestk; idx_int[row] = bestk; }
    }
}

// ===== K8: scatter raw-x sums + counts =====
__global__ __launch_bounds__(256) void k_scatter(const float* __restrict__ x,
                                                 const int* __restrict__ idx_int,
                                                 float* __restrict__ ws) {
    float* counts = ws + WS_COUNTS;
    float* dwraw  = ws + WS_DWRAW;
    const int t = threadIdx.x;
    for (int r = blockIdx.x; r < NROWS; r += gridDim.x) {
        const int k = idx_int[r];
        atomicAdd(&dwraw[(size_t)k * DDIM + t], x[(size_t)r * DDIM + t]);
        if (t == 0) atomicAdd(&counts[k], 1.0f);
    }
}

// ===== K9a: EMA cluster size + n_total =====
__global__ __launch_bounds__(256) void k_ema_cs(const float* __restrict__ cs_in,
                                                float* __restrict__ ws) {
    __shared__ float red[256];
    const int t = threadIdx.x;
    float part = 0.f;
    for (int k = t; k < KDIM; k += 256) {
        const float ncs = cs_in[k] * DECAYV + (1.0f - DECAYV) * ws[WS_COUNTS + k];
        ws[WS_NCSRAW + k] = ncs;
        part += ncs;
    }
    red[t] = part;
    __syncthreads();
    for (int s = 128; s > 0; s >>= 1) { if (t < s) red[t] += red[t + s]; __syncthreads(); }
    if (t == 0) ws[WS_NTOT] = red[0];
}

// ===== K9b: finalize [K,D] outputs =====
__global__ __launch_bounds__(256) void k_final(const float* __restrict__ ema_w,
                                               const float* __restrict__ ws,
                                               float* __restrict__ out) {
    const int k = blockIdx.x;
    const int d = threadIdx.x;
    const float ntot = ws[WS_NTOT];
    const float ncs  = (ws[WS_NCSRAW + k] + 1e-5f) / (ntot + (float)KDIM * 1e-5f) * ntot;
    const float cntk = ws[WS_COUNTS + k];
    const float mn   = ws[WS_MEAN + d];
    const float rs   = ws[WS_RSTD + d];
    const size_t e   = (size_t)k * DDIM + d;
    const float dw   = (ws[WS_DWRAW + e] - cntk * mn) * rs;
    const float nw   = ema_w[e] * DECAYV + (1.0f - DECAYV) * dw;
    const float nemb = nw / ncs;
    const float eo   = nemb * sqrtf(ws[WS_NRVAR + d] + EPSV) + ws[WS_NRMEAN + d];
    out[O_EMB + e]  = nemb;
    out[O_EOUT + e] = eo;
    out[O_EMAW + e] = nw;
    if (d == 0) out[O_CS + k] = ncs;
}

// ===== launcher =====
extern "C" void kernel_launch(void* const* d_in, const int* in_sizes, int n_in,
                              void* d_out, int out_size, void* d_ws, size_t ws_size,
                              hipStream_t stream) {
    const float* x     = (const float*)d_in[0];
    const float* emb   = (const float*)d_in[1];
    const float* cs    = (const float*)d_in[2];
    const float* ema_w = (const float*)d_in[3];
    const float* rmean = (const float*)d_in[4];
    const float* rvar  = (const float*)d_in[5];
    float* out = (float*)d_out;
    float* ws  = (float*)d_ws;

    // zero cnt + nflag + counts + dwraw (contiguous at ws base)
    hipMemsetAsync(ws, 0, WS_ZEND * sizeof(float), stream);

    k_bnpack<<<256, 128, 0, stream>>>(x, ws);
    k_bn_final<<<1, 256, 0, stream>>>(rmean, rvar, ws, out);
    k_eprime<<<KDIM, 128, 0, stream>>>(emb, ws);

    constexpr int LDSB = 65536;
    hipFuncSetAttribute(reinterpret_cast<const void*>(&k_gemm_min),
                        hipFuncAttributeMaxDynamicSharedMemorySize, LDSB);
    hipFuncSetAttribute(reinterpret_cast<const void*>(&k_cand),
                        hipFuncAttributeMaxDynamicSharedMemorySize, LDSB);

    k_gemm_min<<<512, 256, LDSB, stream>>>(ws);
    k_flag<<<NROWS / 256, 256, 0, stream>>>(ws, out);
    k_cand<<<256, 256, LDSB, stream>>>(ws);
    k_resolve_f<<<256, 256, 0, stream>>>(x, ws, out);
    k_scatter<<<2048, 256, 0, stream>>>(x, (const int*)(ws + WS_IDX), ws);
    k_ema_cs<<<1, 256, 0, stream>>>(cs, ws);
    k_final<<<KDIM, 256, 0, stream>>>(ema_w, ws, out);
}

// Round 4
// 412.969 us; speedup vs baseline: 10.2797x; 1.4271x over previous
//
#include <hip/hip_runtime.h>
#include <cfloat>
#include <cmath>

#define NROWS 65536
#define DDIM 256
#define KDIM 4096

typedef short bf16x8 __attribute__((ext_vector_type(8)));
typedef float f32x4 __attribute__((ext_vector_type(4)));

constexpr float EPSV = 1e-5f;
constexpr float DECAYV = 0.99f;
constexpr float MOMV = 0.1f;
constexpr float DELTA = 0.4f;   // bf16 GEMM noise sigma~0.03; 0.4 >= 12 sigma, >= 2*eps
constexpr int CAP = 16;
constexpr int NREP = 4;         // scatter privatization replicas

// ---------------- workspace layout (float offsets) ----------------
constexpr size_t WS_CNT     = 0;                                   // int[N] cand counts (zeroed)
constexpr size_t WS_NFLAG   = WS_CNT + NROWS;                      // int[1] (+pad, zeroed)
constexpr size_t WS_COUNTS  = WS_NFLAG + 64;                       // float[NREP][K] (zeroed)
constexpr size_t WS_DWRAW   = WS_COUNTS + (size_t)NREP * KDIM;     // float[NREP][K*D] (zeroed)
constexpr size_t WS_ZEND    = WS_DWRAW + (size_t)NREP * KDIM * DDIM;
constexpr size_t WS_PARTSUM = WS_ZEND;                             // [256][256]
constexpr size_t WS_PARTSQ  = WS_PARTSUM + 256 * DDIM;             // [256][256]
constexpr size_t WS_MEAN    = WS_PARTSQ + 256 * DDIM;              // [256]
constexpr size_t WS_RSTD    = WS_MEAN + DDIM;                      // [256]
constexpr size_t WS_NRMEAN  = WS_RSTD + DDIM;                      // [256]
constexpr size_t WS_NRVAR   = WS_NRMEAN + DDIM;                    // [256]
constexpr size_t WS_BVEC    = WS_NRVAR + DDIM;                     // [4096]
constexpr size_t WS_NCSRAW  = WS_BVEC + KDIM;                      // [4096]
constexpr size_t WS_CSUM    = WS_NCSRAW + KDIM;                    // [4096]
constexpr size_t WS_NTOT    = WS_CSUM + KDIM;                      // [1] + pad
constexpr size_t WS_ROWINFO = WS_NTOT + 64;                        // float4[N][2]
constexpr size_t WS_IDX     = WS_ROWINFO + 8 * (size_t)NROWS;      // int[N]
constexpr size_t WS_ROWTHR  = WS_IDX + NROWS;                      // float[N]
constexpr size_t WS_FLAG    = WS_ROWTHR + NROWS;                   // int[N]
constexpr size_t WS_CAND    = WS_FLAG + NROWS;                     // int[N*CAP]
constexpr size_t WS_EPROW   = WS_CAND + (size_t)NROWS * CAP;       // float[K][D] e' rows
constexpr size_t WS_EIMG    = WS_EPROW + (size_t)KDIM * DDIM;      // bf16 E image 2MB
constexpr size_t WS_XIMG    = WS_EIMG + 524288;                    // bf16 X image 32MB

// ---------------- output layout (float offsets) ----------------
constexpr size_t O_IDX   = 0;
constexpr size_t O_EMB   = NROWS;
constexpr size_t O_EOUT  = O_EMB + (size_t)KDIM * DDIM;
constexpr size_t O_CS    = O_EOUT + (size_t)KDIM * DDIM;
constexpr size_t O_EMAW  = O_CS + KDIM;
constexpr size_t O_RMEAN = O_EMAW + (size_t)KDIM * DDIM;
constexpr size_t O_RVAR  = O_RMEAN + DDIM;

__device__ inline unsigned bfpack(float a, float b) {   // RNE f32->bf16 pair
    unsigned ua = __float_as_uint(a), ub = __float_as_uint(b);
    ua = (ua + 0x7FFFu + ((ua >> 16) & 1u)) >> 16;
    ub = (ub + 0x7FFFu + ((ub >> 16) & 1u)) & 0xFFFF0000u;
    return (ua & 0xFFFFu) | ub;
}

#define GLOAD_LDS16(g, l) __builtin_amdgcn_global_load_lds(                       \
        (const __attribute__((address_space(1))) void*)(g),                        \
        (__attribute__((address_space(3))) void*)(l), 16, 0, 0)

// ===== K1: BN partial sums + fused x -> bf16 rotated image =====
__global__ __launch_bounds__(128) void k_bnpack(const float* __restrict__ x,
                                                float* __restrict__ ws) {
    const int t = threadIdx.x;      // d-pair 0..127
    const int b = blockIdx.x;       // 256
    char* ximg = (char*)(ws + WS_XIMG);
    float s0 = 0.f, s1 = 0.f, q0 = 0.f, q1 = 0.f;
    for (int r = b; r < NROWS; r += 256) {
        const float2 v = *(const float2*)(x + (size_t)r * DDIM + 2 * t);
        s0 += v.x; s1 += v.y; q0 += v.x * v.x; q1 += v.y * v.y;
        const int db = (4 * t + ((r & 15) << 5)) & 511;
        *(unsigned*)(ximg + (size_t)r * 512 + db) = bfpack(v.x, v.y);
    }
    *(float2*)(ws + WS_PARTSUM + (size_t)b * DDIM + 2 * t) = make_float2(s0, s1);
    *(float2*)(ws + WS_PARTSQ  + (size_t)b * DDIM + 2 * t) = make_float2(q0, q1);
}

// ===== K2: finalize BN stats =====
__global__ __launch_bounds__(256) void k_bn_final(const float* __restrict__ rmean_in,
                                                  const float* __restrict__ rvar_in,
                                                  float* __restrict__ ws,
                                                  float* __restrict__ out) {
    const int d = threadIdx.x;
    float s = 0.f, sq = 0.f;
    for (int b = 0; b < 256; ++b) {
        s  += ws[WS_PARTSUM + (size_t)b * DDIM + d];
        sq += ws[WS_PARTSQ  + (size_t)b * DDIM + d];
    }
    const float mean = s / (float)NROWS;
    float var = sq / (float)NROWS - mean * mean;
    var = fmaxf(var, 0.f);
    const float rstd = 1.0f / sqrtf(var + EPSV);
    const float nrm  = (1.0f - MOMV) * rmean_in[d] + MOMV * mean;
    const float varu = var * ((float)NROWS / (float)(NROWS - 1));
    const float nrv  = (1.0f - MOMV) * rvar_in[d] + MOMV * varu;
    ws[WS_MEAN + d] = mean;
    ws[WS_RSTD + d] = rstd;
    ws[WS_NRMEAN + d] = nrm;
    ws[WS_NRVAR + d] = nrv;
    out[O_RMEAN + d] = nrm;
    out[O_RVAR + d] = nrv;
}

// ===== K3: e' fp32 rows + bf16 rotated image + b_k =====
__global__ __launch_bounds__(128) void k_eprime(const float* __restrict__ emb,
                                                float* __restrict__ ws) {
    __shared__ float red[128];
    const int k = blockIdx.x, t = threadIdx.x;
    const int d0 = 2 * t, d1 = 2 * t + 1;
    const float em0 = emb[(size_t)k * DDIM + d0], em1 = emb[(size_t)k * DDIM + d1];
    const float rs0 = ws[WS_RSTD + d0], rs1 = ws[WS_RSTD + d1];
    const float mn0 = ws[WS_MEAN + d0], mn1 = ws[WS_MEAN + d1];
    const float e0 = em0 * rs0, e1 = em1 * rs1;
    ws[WS_EPROW + (size_t)k * DDIM + d0] = e0;
    ws[WS_EPROW + (size_t)k * DDIM + d1] = e1;
    char* img = (char*)(ws + WS_EIMG);
    const int db = (4 * t + ((k & 15) << 5)) & 511;
    *(unsigned*)(img + (size_t)k * 512 + db) = bfpack(e0, e1);
    red[t] = em0 * em0 + 2.f * mn0 * e0 + em1 * em1 + 2.f * mn1 * e1;
    __syncthreads();
    for (int s = 64; s > 0; s >>= 1) { if (t < s) red[t] += red[t + s]; __syncthreads(); }
    if (t == 0) ws[WS_BVEC + k] = red[0];
}

// ===== K4: single-pass MFMA GEMM, unpacked top-2, col-halved grid =====
// 1024 blocks = 512 row-tiles x 2 col-halves; 4 waves x 32 rows each.
// LDS: 2 x 16KB (32-col chunks) -> 32KB/block -> 4-5 blocks/CU.
__global__ __launch_bounds__(256) void k_gemm_min(float* __restrict__ ws) {
    extern __shared__ char smem[];      // 2 x 16384
    const int t = threadIdx.x, lane = t & 63, w = t >> 6;
    const int l4 = lane & 15, kg = lane >> 4;
    const int tile = blockIdx.x >> 1;
    const int chh  = blockIdx.x & 1;
    const int rowbase = tile * 128 + w * 32;
    const char* ximg = (const char*)(ws + WS_XIMG);
    const char* eimg = (const char*)(ws + WS_EIMG) + (size_t)chh * 1048576;  // 2048 cols
    const float* bvec = ws + WS_BVEC;

    // A fragments: rows rowbase + m*16 + l4, all 8 k-steps (rotated image)
    bf16x8 a[2][8];
#pragma unroll
    for (int m = 0; m < 2; ++m) {
        const char* rp = ximg + (size_t)(rowbase + m * 16 + l4) * 512;
#pragma unroll
        for (int ts = 0; ts < 8; ++ts) {
            const int byte = ((kg * 16 + ts * 64) + (l4 << 5)) & 511;
            a[m][ts] = *(const bf16x8*)(rp + byte);
        }
    }

    float b1v[2][4], b2v[2][4];
    int b1i[2][4];
#pragma unroll
    for (int m = 0; m < 2; ++m)
#pragma unroll
        for (int r = 0; r < 4; ++r) { b1v[m][r] = FLT_MAX; b2v[m][r] = FLT_MAX; b1i[m][r] = 0; }

    // prologue: stage chunk 0 (16KB)
#pragma unroll
    for (int rr = 0; rr < 4; ++rr) {
        const int off = rr * 4096 + w * 1024;
        GLOAD_LDS16(eimg + off + lane * 16, smem + off);
    }
    __syncthreads();

    for (int ch = 0; ch < 64; ++ch) {
        const char* cur = smem + (ch & 1) * 16384;
        if (ch + 1 < 64) {
            const char* src = eimg + (size_t)(ch + 1) * 16384;
            char* nb = smem + ((ch + 1) & 1) * 16384;
#pragma unroll
            for (int rr = 0; rr < 4; ++rr) {
                const int off = rr * 4096 + w * 1024;
                GLOAD_LDS16(src + off + lane * 16, nb + off);
            }
        }

        f32x4 acc[2][2];
#pragma unroll
        for (int m = 0; m < 2; ++m)
#pragma unroll
            for (int n = 0; n < 2; ++n) acc[m][n] = 0.f;

#pragma unroll
        for (int ts = 0; ts < 8; ++ts) {
            const int rot = ((kg * 16 + ts * 64) + (l4 << 5)) & 511;
            bf16x8 bfr[2];
#pragma unroll
            for (int n = 0; n < 2; ++n)
                bfr[n] = *(const bf16x8*)(cur + (n * 16 + l4) * 512 + rot);
#pragma unroll
            for (int m = 0; m < 2; ++m)
#pragma unroll
                for (int n = 0; n < 2; ++n)
                    acc[m][n] = __builtin_amdgcn_mfma_f32_16x16x32_bf16(a[m][ts], bfr[n], acc[m][n], 0, 0, 0);
        }

#pragma unroll
        for (int n = 0; n < 2; ++n) {
            const int col = chh * 2048 + ch * 32 + n * 16 + l4;
            const float bc = bvec[col];
#pragma unroll
            for (int m = 0; m < 2; ++m)
#pragma unroll
                for (int r = 0; r < 4; ++r) {
                    const float s = fmaf(-2.f, acc[m][n][r], bc);
                    const bool lt = s < b1v[m][r];
                    b2v[m][r] = lt ? b1v[m][r] : fminf(b2v[m][r], s);
                    b1i[m][r] = lt ? col : b1i[m][r];
                    b1v[m][r] = lt ? s : b1v[m][r];
                }
        }
        __syncthreads();   // drains prefetch + protects cur reuse
    }

    // merge top-2 across the 16 l4-lanes holding each row; write partial
    float4* rowinfo = (float4*)(ws + WS_ROWINFO);
#pragma unroll
    for (int m = 0; m < 2; ++m)
#pragma unroll
        for (int r = 0; r < 4; ++r) {
            float v1 = b1v[m][r], v2 = b2v[m][r];
            int i1 = b1i[m][r];
#pragma unroll
            for (int st = 1; st < 16; st <<= 1) {
                const float o1 = __shfl_xor(v1, st);
                const int   oi = __shfl_xor(i1, st);
                const float o2 = __shfl_xor(v2, st);
                const bool lt = o1 < v1;
                v2 = lt ? fminf(v1, o2) : fminf(v2, o1);
                i1 = lt ? oi : i1;
                v1 = fminf(v1, o1);
            }
            if (l4 == 0) {
                const int row = rowbase + m * 16 + kg * 4 + r;
                rowinfo[(size_t)row * 2 + chh] =
                    make_float4(v1, __int_as_float(i1), v2, 0.f);
            }
        }
}

// ===== K5: merge col-half partials, flag close rows, decide clear rows =====
__global__ __launch_bounds__(256) void k_flag(float* __restrict__ ws,
                                              float* __restrict__ out) {
    const int r = blockIdx.x * 256 + threadIdx.x;
    const float4* rowinfo = (const float4*)(ws + WS_ROWINFO);
    const float4 p0 = rowinfo[(size_t)r * 2];
    const float4 p1 = rowinfo[(size_t)r * 2 + 1];
    const bool lt = p1.x < p0.x;
    const float v1 = lt ? p1.x : p0.x;
    const int   i1 = __float_as_int(lt ? p1.y : p0.y);
    const float v2 = lt ? fminf(p0.x, p1.z) : fminf(p1.x, p0.z);
    ws[WS_ROWTHR + r] = v1 + DELTA;
    if (v2 - v1 <= DELTA) {
        const int pos = atomicAdd((int*)(ws + WS_NFLAG), 1);
        ((int*)(ws + WS_FLAG))[pos] = r;
    } else {
        out[O_IDX + r] = (float)i1;
        ((int*)(ws + WS_IDX))[r] = i1;
    }
}

// ===== K6: candidate-append mini-GEMM over flagged rows, col-sliced x8 =====
__global__ __launch_bounds__(256) void k_cand(float* __restrict__ ws) {
    extern __shared__ char smem[];      // 2 x 16384
    const int t = threadIdx.x, lane = t & 63, w = t >> 6;
    const int l4 = lane & 15, kg = lane >> 4;
    const char* ximg = (const char*)(ws + WS_XIMG);
    const char* eimg0 = (const char*)(ws + WS_EIMG);
    const float* bvec = ws + WS_BVEC;
    const int* flag = (const int*)(ws + WS_FLAG);
    int* cnt = (int*)(ws + WS_CNT);
    int* cand = (int*)(ws + WS_CAND);
    const int nflag = *(const int*)(ws + WS_NFLAG);
    if (nflag == 0) return;
    const int ntiles = (nflag + 127) >> 7;
    const int nitems = ntiles * 8;

    for (int item = blockIdx.x; item < nitems; item += gridDim.x) {
        const int tile = item >> 3, slice = item & 7;
        const int base = tile * 128 + w * 32;
        const char* eimg = eimg0 + (size_t)slice * 262144;   // 512 cols per slice
        bf16x8 a[2][8];
        int frow[2][4];
        float thr[2][4];
#pragma unroll
        for (int m = 0; m < 2; ++m) {
            const int ia = base + m * 16 + l4;
            const int rowa = flag[ia < nflag ? ia : (nflag - 1)];
            const char* rp = ximg + (size_t)rowa * 512;
#pragma unroll
            for (int ts = 0; ts < 8; ++ts) {
                const int byte = ((kg * 16 + ts * 64) + ((rowa & 15) << 5)) & 511;
                a[m][ts] = *(const bf16x8*)(rp + byte);
            }
#pragma unroll
            for (int r = 0; r < 4; ++r) {
                const int ie = base + m * 16 + kg * 4 + r;
                const bool val = ie < nflag;
                const int rowe = flag[val ? ie : (nflag - 1)];
                frow[m][r] = rowe;
                thr[m][r] = val ? ws[WS_ROWTHR + rowe] : -FLT_MAX;
            }
        }
#pragma unroll
        for (int rr = 0; rr < 4; ++rr) {
            const int off = rr * 4096 + w * 1024;
            GLOAD_LDS16(eimg + off + lane * 16, smem + off);
        }
        __syncthreads();

        for (int ch = 0; ch < 16; ++ch) {
            const char* cur = smem + (ch & 1) * 16384;
            if (ch + 1 < 16) {
                const char* src = eimg + (size_t)(ch + 1) * 16384;
                char* nb = smem + ((ch + 1) & 1) * 16384;
#pragma unroll
                for (int rr = 0; rr < 4; ++rr) {
                    const int off = rr * 4096 + w * 1024;
                    GLOAD_LDS16(src + off + lane * 16, nb + off);
                }
            }
            f32x4 acc[2][2];
#pragma unroll
            for (int m = 0; m < 2; ++m)
#pragma unroll
                for (int n = 0; n < 2; ++n) acc[m][n] = 0.f;
#pragma unroll
            for (int ts = 0; ts < 8; ++ts) {
                const int rot = ((kg * 16 + ts * 64) + (l4 << 5)) & 511;
                bf16x8 bfr[2];
#pragma unroll
                for (int n = 0; n < 2; ++n)
                    bfr[n] = *(const bf16x8*)(cur + (n * 16 + l4) * 512 + rot);
#pragma unroll
                for (int m = 0; m < 2; ++m)
#pragma unroll
                    for (int n = 0; n < 2; ++n)
                        acc[m][n] = __builtin_amdgcn_mfma_f32_16x16x32_bf16(a[m][ts], bfr[n], acc[m][n], 0, 0, 0);
            }
#pragma unroll
            for (int n = 0; n < 2; ++n) {
                const int col = slice * 512 + ch * 32 + n * 16 + l4;
                const float bc = bvec[col];
#pragma unroll
                for (int m = 0; m < 2; ++m)
#pragma unroll
                    for (int r = 0; r < 4; ++r) {
                        const float s = fmaf(-2.f, acc[m][n][r], bc);
                        if (s <= thr[m][r]) {
                            const int rr2 = frow[m][r];
                            const int pos = atomicAdd(&cnt[rr2], 1);
                            if (pos < CAP) cand[(size_t)rr2 * CAP + pos] = col;
                        }
                    }
            }
            __syncthreads();
        }
    }
}

// ===== K7: exact fp32 resolve for flagged rows =====
__global__ __launch_bounds__(256) void k_resolve_f(const float* __restrict__ x,
                                                   float* __restrict__ ws,
                                                   float* __restrict__ out) {
    const int t = threadIdx.x, lane = t & 63;
    const int gw = (blockIdx.x * 256 + t) >> 6;     // 1024 waves
    const int nflag = *(const int*)(ws + WS_NFLAG);
    const int* flag = (const int*)(ws + WS_FLAG);
    const int* cnt = (const int*)(ws + WS_CNT);
    const int* cand = (const int*)(ws + WS_CAND);
    const float* eprow = ws + WS_EPROW;
    const float* bvec = ws + WS_BVEC;
    int* idx_int = (int*)(ws + WS_IDX);
    for (int i = gw; i < nflag; i += 1024) {
        const int row = flag[i];
        const float4 xr = ((const float4*)(x + (size_t)row * DDIM))[lane];
        const int n = cnt[row];
        float bestv = FLT_MAX;
        int bestk = KDIM;
        if (n >= 1 && n <= CAP) {
            for (int c = 0; c < n; ++c) {
                const int k = cand[(size_t)row * CAP + c];
                const float4 er = ((const float4*)(eprow + (size_t)k * DDIM))[lane];
                float p = xr.x * er.x + xr.y * er.y + xr.z * er.z + xr.w * er.w;
                p += __shfl_xor(p, 32); p += __shfl_xor(p, 16); p += __shfl_xor(p, 8);
                p += __shfl_xor(p, 4);  p += __shfl_xor(p, 2);  p += __shfl_xor(p, 1);
                const float s = fmaf(-2.f, p, bvec[k]);
                if (s < bestv || (s == bestv && k < bestk)) { bestv = s; bestk = k; }
            }
        } else {   // overflow / safety fallback: exact full scan
            for (int k = 0; k < KDIM; ++k) {
                const float4 er = ((const float4*)(eprow + (size_t)k * DDIM))[lane];
                float p = xr.x * er.x + xr.y * er.y + xr.z * er.z + xr.w * er.w;
                p += __shfl_xor(p, 32); p += __shfl_xor(p, 16); p += __shfl_xor(p, 8);
                p += __shfl_xor(p, 4);  p += __shfl_xor(p, 2);  p += __shfl_xor(p, 1);
                const float s = fmaf(-2.f, p, bvec[k]);
                if (s < bestv || (s == bestv && k < bestk)) { bestv = s; bestk = k; }
            }
        }
        if (lane == 0) { out[O_IDX + row] = (float)bestk; idx_int[row] = bestk; }
    }
}

// ===== K8: scatter raw-x sums + counts (4 privatized replicas) =====
__global__ __launch_bounds__(256) void k_scatter(const float* __restrict__ x,
                                                 const int* __restrict__ idx_int,
                                                 float* __restrict__ ws) {
    const int rep = blockIdx.x & (NREP - 1);
    float* counts = ws + WS_COUNTS + (size_t)rep * KDIM;
    float* dwraw  = ws + WS_DWRAW + (size_t)rep * KDIM * DDIM;
    const int t = threadIdx.x;
    for (int r = blockIdx.x; r < NROWS; r += gridDim.x) {
        const int k = idx_int[r];
        atomicAdd(&dwraw[(size_t)k * DDIM + t], x[(size_t)r * DDIM + t]);
        if (t == 0) atomicAdd(&counts[k], 1.0f);
    }
}

// ===== K9a: sum count replicas, EMA cluster size + n_total =====
__global__ __launch_bounds__(256) void k_ema_cs(const float* __restrict__ cs_in,
                                                float* __restrict__ ws) {
    __shared__ float red[256];
    const int t = threadIdx.x;
    float part = 0.f;
    for (int k = t; k < KDIM; k += 256) {
        float c = 0.f;
#pragma unroll
        for (int rep = 0; rep < NREP; ++rep) c += ws[WS_COUNTS + (size_t)rep * KDIM + k];
        ws[WS_CSUM + k] = c;
        const float ncs = cs_in[k] * DECAYV + (1.0f - DECAYV) * c;
        ws[WS_NCSRAW + k] = ncs;
        part += ncs;
    }
    red[t] = part;
    __syncthreads();
    for (int s = 128; s > 0; s >>= 1) { if (t < s) red[t] += red[t + s]; __syncthreads(); }
    if (t == 0) ws[WS_NTOT] = red[0];
}

// ===== K9b: finalize [K,D] outputs =====
__global__ __launch_bounds__(256) void k_final(const float* __restrict__ ema_w,
                                               const float* __restrict__ ws,
                                               float* __restrict__ out) {
    const int k = blockIdx.x;
    const int d = threadIdx.x;
    const float ntot = ws[WS_NTOT];
    const float ncs  = (ws[WS_NCSRAW + k] + 1e-5f) / (ntot + (float)KDIM * 1e-5f) * ntot;
    const float cntk = ws[WS_CSUM + k];
    const float mn   = ws[WS_MEAN + d];
    const float rs   = ws[WS_RSTD + d];
    const size_t e   = (size_t)k * DDIM + d;
    float dwsum = 0.f;
#pragma unroll
    for (int rep = 0; rep < NREP; ++rep)
        dwsum += ws[WS_DWRAW + (size_t)rep * KDIM * DDIM + e];
    const float dw   = (dwsum - cntk * mn) * rs;
    const float nw   = ema_w[e] * DECAYV + (1.0f - DECAYV) * dw;
    const float nemb = nw / ncs;
    const float eo   = nemb * sqrtf(ws[WS_NRVAR + d] + EPSV) + ws[WS_NRMEAN + d];
    out[O_EMB + e]  = nemb;
    out[O_EOUT + e] = eo;
    out[O_EMAW + e] = nw;
    if (d == 0) out[O_CS + k] = ncs;
}

// ===== launcher =====
extern "C" void kernel_launch(void* const* d_in, const int* in_sizes, int n_in,
                              void* d_out, int out_size, void* d_ws, size_t ws_size,
                              hipStream_t stream) {
    const float* x     = (const float*)d_in[0];
    const float* emb   = (const float*)d_in[1];
    const float* cs    = (const float*)d_in[2];
    const float* ema_w = (const float*)d_in[3];
    const float* rmean = (const float*)d_in[4];
    const float* rvar  = (const float*)d_in[5];
    float* out = (float*)d_out;
    float* ws  = (float*)d_ws;

    // zero cnt + nflag + count/dw replicas (contiguous at ws base)
    hipMemsetAsync(ws, 0, WS_ZEND * sizeof(float), stream);

    k_bnpack<<<256, 128, 0, stream>>>(x, ws);
    k_bn_final<<<1, 256, 0, stream>>>(rmean, rvar, ws, out);
    k_eprime<<<KDIM, 128, 0, stream>>>(emb, ws);

    constexpr int LDSB = 32768;
    k_gemm_min<<<1024, 256, LDSB, stream>>>(ws);
    k_flag<<<NROWS / 256, 256, 0, stream>>>(ws, out);
    k_cand<<<512, 256, LDSB, stream>>>(ws);
    k_resolve_f<<<256, 256, 0, stream>>>(x, ws, out);
    k_scatter<<<2048, 256, 0, stream>>>(x, (const int*)(ws + WS_IDX), ws);
    k_ema_cs<<<1, 256, 0, stream>>>(cs, ws);
    k_final<<<KDIM, 256, 0, stream>>>(ema_w, ws, out);
}